// Round 10
// baseline (378.305 us; speedup 1.0000x reference)
//
#include <hip/hip_runtime.h>
#include <math.h>

#define B_ 2
#define S_ 2048
#define D_ 1024
#define H_ 16
#define DK_ 64
#define EPS_ 1e-5f

typedef __bf16 bf16_t;
typedef __bf16 bf16x4 __attribute__((ext_vector_type(4)));
typedef __bf16 bf16x8 __attribute__((ext_vector_type(8)));
typedef float f32x4 __attribute__((ext_vector_type(4)));
typedef unsigned long long u64;
typedef unsigned short u16;

#define MFMA16(a, b, c) __builtin_amdgcn_mfma_f32_16x16x32_bf16(a, b, c, 0, 0, 0)

// global -> LDS 16B DMA (global_load_lds_dwordx4). LDS dest is wave-uniform
// base + lane*16; global src is per-lane.
__device__ __forceinline__ void gload16(const bf16_t* g, bf16_t* l) {
    __builtin_amdgcn_global_load_lds(
        (const __attribute__((address_space(1))) void*)g,
        (__attribute__((address_space(3))) void*)l, 16, 0, 0);
}

// ---------------------------------------------------------------------------
// fp32 -> bf16 converters (8 elems/thread).
// ---------------------------------------------------------------------------
__global__ __launch_bounds__(256) void cvt3(const float* __restrict__ a,
        const float* __restrict__ b, const float* __restrict__ c,
        bf16_t* __restrict__ oa, bf16_t* __restrict__ ob, bf16_t* __restrict__ oc)
{
    int region = blockIdx.x >> 11;
    int i = ((blockIdx.x & 2047) << 8) + threadIdx.x;
    const float* in = (region == 0) ? a : (region == 1) ? b : c;
    bf16_t* out = (region == 0) ? oa : (region == 1) ? ob : oc;
    float4 v0 = reinterpret_cast<const float4*>(in)[i * 2];
    float4 v1 = reinterpret_cast<const float4*>(in)[i * 2 + 1];
    bf16x8 o = { (bf16_t)v0.x, (bf16_t)v0.y, (bf16_t)v0.z, (bf16_t)v0.w,
                 (bf16_t)v1.x, (bf16_t)v1.y, (bf16_t)v1.z, (bf16_t)v1.w };
    reinterpret_cast<bf16x8*>(out)[i] = o;
}

__global__ __launch_bounds__(256) void cvt4(const float* __restrict__ a,
        const float* __restrict__ b, const float* __restrict__ c, const float* __restrict__ d,
        bf16_t* __restrict__ oa, bf16_t* __restrict__ ob, bf16_t* __restrict__ oc,
        bf16_t* __restrict__ od)
{
    int region = blockIdx.x >> 9;
    int i = ((blockIdx.x & 511) << 8) + threadIdx.x;
    const float* in = (region == 0) ? a : (region == 1) ? b : (region == 2) ? c : d;
    bf16_t* out = (region == 0) ? oa : (region == 1) ? ob : (region == 2) ? oc : od;
    float4 v0 = reinterpret_cast<const float4*>(in)[i * 2];
    float4 v1 = reinterpret_cast<const float4*>(in)[i * 2 + 1];
    bf16x8 o = { (bf16_t)v0.x, (bf16_t)v0.y, (bf16_t)v0.z, (bf16_t)v0.w,
                 (bf16_t)v1.x, (bf16_t)v1.y, (bf16_t)v1.z, (bf16_t)v1.w };
    reinterpret_cast<bf16x8*>(out)[i] = o;
}

// ---------------------------------------------------------------------------
// Pack int32 mask [B,S,S] into per-(row,g) u16 streams:
// bits2[((b*S+row)*4+g)*32 + t] bit (tk*4+r) = mask[b,row, t*64+tk*16+g*4+r].
// Lane (row,g) then owns a contiguous 64 B mask record for all 32 tiles.
// ---------------------------------------------------------------------------
__global__ __launch_bounds__(256) void mask_pack(const int* __restrict__ mask,
                                                 u16* __restrict__ bits2)
{
    size_t i = (size_t)blockIdx.x * 256 + threadIdx.x;
    int m = mask[i];
    u64 wm = __ballot(m != 0);
    if ((threadIdx.x & 63) == 0) {
        size_t widx = i >> 6;              // (b*S+row)*32 + t
        size_t row = widx >> 5;
        int t = (int)(widx & 31);
#pragma unroll
        for (int g = 0; g < 4; ++g) {
            u16 v = 0;
#pragma unroll
            for (int tk = 0; tk < 4; ++tk)
                v |= (u16)(((wm >> (tk * 16 + g * 4)) & 0xF) << (tk * 4));
            bits2[(row * 4 + g) * 32 + t] = v;
        }
    }
}

// ---------------------------------------------------------------------------
// 128x128-tile bf16 GEMM (unchanged from r9): Y = X @ W^T + bias.
// ---------------------------------------------------------------------------
__global__ __launch_bounds__(256) void gemm_bf16(
        const bf16_t* __restrict__ X, const bf16_t* __restrict__ W,
        const float*  __restrict__ bias, const float* __restrict__ resid,
        float* __restrict__ xout, bf16_t* __restrict__ bout, int mode)
{
    __shared__ bf16_t As[128 * 64];
    __shared__ bf16_t Bs[128 * 64];
    const int tid = threadIdx.x;
    const int w = tid >> 6, l = tid & 63;
    const int c = l & 15, g = l >> 4;
    const int wr = w >> 1, wc = w & 1;
    const int m0 = blockIdx.y * 128, n0 = blockIdx.x * 128;

    const bf16_t* Asrc = (mode == 1) ? (W + (size_t)n0 * D_) : (X + (size_t)m0 * D_);
    const bf16_t* Bsrc = (mode == 1) ? (X + (size_t)m0 * D_) : (W + (size_t)n0 * D_);

    int srow[4], scol[4];
    uint32_t soff[4];
#pragma unroll
    for (int i = 0; i < 4; ++i) {
        int s = tid + i * 256;
        srow[i] = s >> 3;
        scol[i] = s & 7;
        soff[i] = (uint32_t)(s * 16) ^ (uint32_t)((srow[i] & 7) << 4);
    }

    bf16x8 areg[4], breg[4];
#pragma unroll
    for (int i = 0; i < 4; ++i) {
        areg[i] = *reinterpret_cast<const bf16x8*>(Asrc + (size_t)srow[i] * D_ + scol[i] * 8);
        breg[i] = *reinterpret_cast<const bf16x8*>(Bsrc + (size_t)srow[i] * D_ + scol[i] * 8);
    }

    f32x4 acc[4][4] = {};
    for (int kt = 0; kt < 16; ++kt) {
#pragma unroll
        for (int i = 0; i < 4; ++i) {
            *reinterpret_cast<bf16x8*>((char*)As + soff[i]) = areg[i];
            *reinterpret_cast<bf16x8*>((char*)Bs + soff[i]) = breg[i];
        }
        __syncthreads();
        if (kt + 1 < 16) {
            int k0 = (kt + 1) * 64;
#pragma unroll
            for (int i = 0; i < 4; ++i) {
                areg[i] = *reinterpret_cast<const bf16x8*>(Asrc + (size_t)srow[i] * D_ + k0 + scol[i] * 8);
                breg[i] = *reinterpret_cast<const bf16x8*>(Bsrc + (size_t)srow[i] * D_ + k0 + scol[i] * 8);
            }
        }
        bf16x8 bf0[4], bf1[4];
#pragma unroll
        for (int j = 0; j < 4; ++j) {
            int R = wc * 64 + j * 16 + c;
            const char* base = (const char*)Bs + R * 128;
            uint32_t msk = (uint32_t)((R & 7) << 4);
            bf0[j] = *reinterpret_cast<const bf16x8*>(base + ((g * 16) ^ msk));
            bf1[j] = *reinterpret_cast<const bf16x8*>(base + ((64 + g * 16) ^ msk));
        }
#pragma unroll
        for (int i = 0; i < 4; ++i) {
            int R = wr * 64 + i * 16 + c;
            const char* base = (const char*)As + R * 128;
            uint32_t msk = (uint32_t)((R & 7) << 4);
            bf16x8 a0 = *reinterpret_cast<const bf16x8*>(base + ((g * 16) ^ msk));
            bf16x8 a1 = *reinterpret_cast<const bf16x8*>(base + ((64 + g * 16) ^ msk));
#pragma unroll
            for (int j = 0; j < 4; ++j) {
                acc[i][j] = MFMA16(a0, bf0[j], acc[i][j]);
                acc[i][j] = MFMA16(a1, bf1[j], acc[i][j]);
            }
        }
        __syncthreads();
    }

#pragma unroll
    for (int i = 0; i < 4; ++i) {
#pragma unroll
        for (int j = 0; j < 4; ++j) {
#pragma unroll
            for (int r = 0; r < 4; ++r) {
                int P  = wr * 64 + i * 16 + g * 4 + r;
                int Qd = wc * 64 + j * 16 + c;
                float val = acc[i][j][r];
                if (mode == 2) {
                    int m = m0 + P, n = n0 + Qd;
                    xout[(size_t)m * D_ + n] = val + bias[n] + resid[(size_t)m * D_ + n];
                } else if (mode == 0) {
                    int m = m0 + P, n = n0 + Qd;
                    int bb = m >> 11, s = m & (S_ - 1);
                    int h = n >> 6, dk = n & 63;
                    bout[(((size_t)bb * H_ + h) * S_ + s) * DK_ + dk] = (bf16_t)(val + bias[n]);
                } else {
                    int n = n0 + P, m = m0 + Qd;
                    int bb = m >> 11, s = m & (S_ - 1);
                    int h = n >> 6, dk = n & 63;
                    bout[(((size_t)bb * H_ + h) * DK_ + dk) * S_ + s] = (bf16_t)(val + bias[n]);
                }
            }
        }
    }
}

// ---------------------------------------------------------------------------
// Fused attention: no-max softmax, K/V staged via global_load_lds DMA
// (inverse-swizzled global source, linear LDS dest, XOR read — rule #21),
// raw s_barrier with counted vmcnt (stores stay in flight, T3/T4),
// mask preloaded into 8 u64 regs per lane (no in-loop global loads).
// ---------------------------------------------------------------------------
__global__ __launch_bounds__(512) void fused_attn(
        const bf16_t* __restrict__ qh,   // [B,H,S,DK]
        const bf16_t* __restrict__ kh,   // [B,H,S,DK]
        const bf16_t* __restrict__ vt,   // [B,H,DK,S]
        const u16*    __restrict__ bits2,// [B*S*4][32] u16
        float* __restrict__ attn,        // [B,H,S,S]
        bf16_t* __restrict__ ctx)        // [B,S,D] bf16
{
    constexpr int TILE = 64;
    constexpr int NT = S_ / TILE;        // 32
    __shared__ bf16_t Kbuf[2][TILE * DK_];   // 2 x 8 KB
    __shared__ bf16_t Vbuf[2][TILE * DK_];   // 2 x 8 KB
    __shared__ bf16_t Ps[8][16][72];         // 18 KB wave-private P staging

    const int tid = threadIdx.x;
    const int w = tid >> 6, l = tid & 63;
    const int c = l & 15, g = l >> 4;

    const int id = blockIdx.x;
    const int xcd = id & 7, ixd = id >> 3;
    const int bh = xcd * 4 + (ixd >> 4);
    const int qt = ixd & 15;
    const int q0 = qt * 128 + w * 16;
    const int b = bh >> 4, h = bh & 15;

    const bf16_t* Q = qh + ((size_t)bh * S_ + q0) * DK_;
    const bf16_t* K = kh + (size_t)bh * S_ * DK_;
    const bf16_t* V = vt + (size_t)bh * DK_ * S_;
    float* A = attn + ((size_t)bh * S_ + q0 + c) * S_;

    // mask record: 64 B per lane, all 32 tiles
    u64 mreg[8];
    {
        const u64* mp = reinterpret_cast<const u64*>(
            bits2 + (((size_t)b * S_ + q0 + c) * 4 + g) * 32);
#pragma unroll
        for (int i = 0; i < 8; ++i) mreg[i] = mp[i];
    }

    // Q fragment (B-operand), resident both passes
    bf16x8 qf0 = *reinterpret_cast<const bf16x8*>(&Q[c * DK_ + g * 8]);
    bf16x8 qf1 = *reinterpret_cast<const bf16x8*>(&Q[c * DK_ + 32 + g * 8]);

    // DMA staging geometry: wave w stages LDS slots [w*64, w*64+64) (1 KB).
    // slot s: row = s>>3, colslot = s&7. Global source pre-swizzled:
    // global col slot = colslot ^ (row&7)  (involution; read side XORs same).
    const int row_s = (w << 3) + (l >> 3);   // 0..63
    const int csx = (l & 7) ^ (row_s & 7);
    const bf16_t* Kg = K + (size_t)row_s * DK_ + csx * 8;  // + t*64*DK_
    const bf16_t* Vg = V + (size_t)row_s * S_ + csx * 8;   // + t*64
    const int woffu = __builtin_amdgcn_readfirstlane(w * 512);  // bf16 elems
    const uint32_t rm = (uint32_t)((c & 7) << 4);   // read-side XOR mask

    //================= pass 1: row sums of exp =================
    int cur = 0;
    gload16(Kg, &Kbuf[0][woffu]);
    asm volatile("s_waitcnt vmcnt(0)" ::: "memory");
    __builtin_amdgcn_s_barrier();

    float l_r = 0.f;
    for (int t = 0; t < NT; ++t) {
        if (t + 1 < NT)
            gload16(Kg + (size_t)(t + 1) * TILE * DK_, &Kbuf[cur ^ 1][woffu]);
        __builtin_amdgcn_sched_barrier(0);
        u16 m16 = (u16)(mreg[t >> 2] >> ((t & 3) << 4));
        const char* kb = (const char*)&Kbuf[cur][0];
        f32x4 acc[4] = {};
#pragma unroll
        for (int tk = 0; tk < 4; ++tk) {
            uint32_t base = (uint32_t)((tk * 16 + c) * 128 + g * 16);
            bf16x8 a0 = *reinterpret_cast<const bf16x8*>(kb + (base ^ rm));
            bf16x8 a1 = *reinterpret_cast<const bf16x8*>(kb + ((base + 64) ^ rm));
            acc[tk] = MFMA16(a0, qf0, acc[tk]);
            acc[tk] = MFMA16(a1, qf1, acc[tk]);
        }
        float ps = 0.f;
#pragma unroll
        for (int tk = 0; tk < 4; ++tk) {
#pragma unroll
            for (int r = 0; r < 4; ++r) {
                float e = __expf(acc[tk][r] * 0.125f);
                e = ((m16 >> (tk * 4 + r)) & 1) ? e : 0.f;
                ps += e;
            }
        }
        l_r += ps;
        asm volatile("s_waitcnt vmcnt(0)" ::: "memory");
        asm volatile("s_waitcnt lgkmcnt(0)" ::: "memory");
        __builtin_amdgcn_sched_barrier(0);
        __builtin_amdgcn_s_barrier();
        cur ^= 1;
    }
    l_r += __shfl_xor(l_r, 16);
    l_r += __shfl_xor(l_r, 32);
    const float inv_l = 1.0f / l_r;

    //================= pass 2: emit P + PV =================
    cur = 0;
    gload16(Kg, &Kbuf[0][woffu]);
    gload16(Vg, &Vbuf[0][woffu]);
    asm volatile("s_waitcnt vmcnt(0)" ::: "memory");
    __builtin_amdgcn_s_barrier();

    f32x4 oacc[4] = {};
    for (int t = 0; t < NT; ++t) {
        if (t + 1 < NT) {
            gload16(Kg + (size_t)(t + 1) * TILE * DK_, &Kbuf[cur ^ 1][woffu]);
            gload16(Vg + (t + 1) * TILE, &Vbuf[cur ^ 1][woffu]);
        }
        __builtin_amdgcn_sched_barrier(0);
        u16 m16 = (u16)(mreg[t >> 2] >> ((t & 3) << 4));
        const char* kb = (const char*)&Kbuf[cur][0];
        const char* vb = (const char*)&Vbuf[cur][0];
        f32x4 acc[4] = {};
#pragma unroll
        for (int tk = 0; tk < 4; ++tk) {
            uint32_t base = (uint32_t)((tk * 16 + c) * 128 + g * 16);
            bf16x8 a0 = *reinterpret_cast<const bf16x8*>(kb + (base ^ rm));
            bf16x8 a1 = *reinterpret_cast<const bf16x8*>(kb + ((base + 64) ^ rm));
            acc[tk] = MFMA16(a0, qf0, acc[tk]);
            acc[tk] = MFMA16(a1, qf1, acc[tk]);
        }
#pragma unroll
        for (int tk = 0; tk < 4; ++tk) {
            f32x4 pv;
            bf16x4 pb;
#pragma unroll
            for (int r = 0; r < 4; ++r) {
                float p = __expf(acc[tk][r] * 0.125f) * inv_l;
                p = ((m16 >> (tk * 4 + r)) & 1) ? p : 0.f;
                pv[r] = p;
                pb[r] = (bf16_t)p;
            }
            *reinterpret_cast<f32x4*>(&A[t * TILE + tk * 16 + g * 4]) = pv;   // 4 stores/lane/tile
            *reinterpret_cast<bf16x4*>(&Ps[w][c][tk * 16 + g * 4]) = pb;
        }
        // wave-private LDS round-trip; DS-queue drain only (no vmcnt)
        asm volatile("s_waitcnt lgkmcnt(0)" ::: "memory");
        bf16x8 pa0 = *reinterpret_cast<const bf16x8*>(&Ps[w][c][g * 8]);
        bf16x8 pa1 = *reinterpret_cast<const bf16x8*>(&Ps[w][c][32 + g * 8]);
#pragma unroll
        for (int tk = 0; tk < 4; ++tk) {
            uint32_t base = (uint32_t)((tk * 16 + c) * 128 + g * 16);
            bf16x8 b0 = *reinterpret_cast<const bf16x8*>(vb + (base ^ rm));
            bf16x8 b1 = *reinterpret_cast<const bf16x8*>(vb + ((base + 64) ^ rm));
            oacc[tk] = MFMA16(pa0, b0, oacc[tk]);
            oacc[tk] = MFMA16(pa1, b1, oacc[tk]);
        }
        // counted drain: own 2 DMAs retired (in-order), 4 A-stores stay in flight
        asm volatile("s_waitcnt vmcnt(4)" ::: "memory");
        asm volatile("s_waitcnt lgkmcnt(0)" ::: "memory");
        __builtin_amdgcn_sched_barrier(0);
        __builtin_amdgcn_s_barrier();
        cur ^= 1;
    }

#pragma unroll
    for (int tk = 0; tk < 4; ++tk) {
#pragma unroll
        for (int r = 0; r < 4; ++r) {
            int q = q0 + g * 4 + r;
            ctx[((size_t)b * S_ + q) * D_ + h * DK_ + tk * 16 + c] = (bf16_t)oacc[tk][r];
        }
    }
}

// ---------------------------------------------------------------------------
// LayerNorm over last dim (1024), 4096 rows
// ---------------------------------------------------------------------------
__global__ void ln_kernel(const float* __restrict__ x, const float* __restrict__ gamma,
                          const float* __restrict__ beta, float* __restrict__ out)
{
    int row = blockIdx.x;
    const float* xr = x + (size_t)row * D_;
    int tid = threadIdx.x;
    float v[4];
    float s = 0.f;
#pragma unroll
    for (int i = 0; i < 4; ++i) {
        v[i] = xr[tid + i * 256];
        s += v[i];
    }
#pragma unroll
    for (int off = 32; off > 0; off >>= 1) s += __shfl_xor(s, off);
    __shared__ float red[4];
    int wid = tid >> 6, lane = tid & 63;
    if (lane == 0) red[wid] = s;
    __syncthreads();
    float mu = (red[0] + red[1] + red[2] + red[3]) * (1.0f / D_);
    float vs = 0.f;
#pragma unroll
    for (int i = 0; i < 4; ++i) {
        float d = v[i] - mu;
        vs += d * d;
    }
#pragma unroll
    for (int off = 32; off > 0; off >>= 1) vs += __shfl_xor(vs, off);
    __syncthreads();
    __shared__ float red2[4];
    if (lane == 0) red2[wid] = vs;
    __syncthreads();
    float var = (red2[0] + red2[1] + red2[2] + red2[3]) * (1.0f / D_);
    float rs = rsqrtf(var + EPS_);
#pragma unroll
    for (int i = 0; i < 4; ++i) {
        int c = tid + i * 256;
        out[(size_t)row * D_ + c] = (v[i] - mu) * rs * gamma[c] + beta[c];
    }
}

extern "C" void kernel_launch(void* const* d_in, const int* in_sizes, int n_in,
                              void* d_out, int out_size, void* d_ws, size_t ws_size,
                              hipStream_t stream) {
    const float* q    = (const float*)d_in[0];
    const float* k    = (const float*)d_in[1];
    const float* v    = (const float*)d_in[2];
    const int*   mask = (const int*)d_in[3];
    const float* Wq   = (const float*)d_in[4];
    const float* bq   = (const float*)d_in[5];
    const float* Wk   = (const float*)d_in[6];
    const float* bk   = (const float*)d_in[7];
    const float* Wv   = (const float*)d_in[8];
    const float* bv   = (const float*)d_in[9];
    const float* Wo   = (const float*)d_in[10];
    const float* bo   = (const float*)d_in[11];
    const float* gamma= (const float*)d_in[12];
    const float* beta = (const float*)d_in[13];

    float* out  = (float*)d_out;                       // [B,S,D]
    float* attn = out + (size_t)B_ * S_ * D_;          // [B,H,S,S]

    uint8_t* ws = (uint8_t*)d_ws;
    bf16_t* xq  = (bf16_t*)(ws);
    bf16_t* xk  = (bf16_t*)(ws + ((size_t)8  << 20));
    bf16_t* xv  = (bf16_t*)(ws + ((size_t)16 << 20));
    bf16_t* wqb = (bf16_t*)(ws + ((size_t)24 << 20));
    bf16_t* wkb = (bf16_t*)(ws + ((size_t)26 << 20));
    bf16_t* wvb = (bf16_t*)(ws + ((size_t)28 << 20));
    bf16_t* wob = (bf16_t*)(ws + ((size_t)30 << 20));
    bf16_t* qh  = (bf16_t*)(ws + ((size_t)32 << 20));
    u16*    bits= (u16*)   (ws + ((size_t)40 << 20));
    bf16_t* kh  = (bf16_t*)(ws);                       // over xq
    bf16_t* vt  = (bf16_t*)(ws + ((size_t)8  << 20));  // over xk
    bf16_t* ctx = (bf16_t*)(ws + ((size_t)16 << 20));  // over xv
    float*  x   = (float*) (ws + ((size_t)32 << 20));  // over qh+bits

    dim3 blk(256);
    cvt3<<<dim3(6144), blk, 0, stream>>>(q, k, v, xq, xk, xv);
    cvt4<<<dim3(2048), blk, 0, stream>>>(Wq, Wk, Wv, Wo, wqb, wkb, wvb, wob);
    mask_pack<<<dim3((B_ * S_ * S_) / 256), blk, 0, stream>>>(mask, bits);

    dim3 ggemm(D_ / 128, (B_ * S_) / 128);             // (8, 32)
    gemm_bf16<<<ggemm, blk, 0, stream>>>(xq, wqb, bq, nullptr, nullptr, qh, 0);
    gemm_bf16<<<ggemm, blk, 0, stream>>>(xk, wkb, bk, nullptr, nullptr, kh, 0);
    gemm_bf16<<<ggemm, blk, 0, stream>>>(xv, wvb, bv, nullptr, nullptr, vt, 1);

    fused_attn<<<dim3(512), dim3(512), 0, stream>>>(qh, kh, vt, bits, attn, ctx);

    gemm_bf16<<<ggemm, blk, 0, stream>>>(ctx, wob, bo, q, x, nullptr, 2);
    ln_kernel<<<dim3(B_ * S_), blk, 0, stream>>>(x, gamma, beta, out);
}

// Round 11
// 365.194 us; speedup vs baseline: 1.0359x; 1.0359x over previous
//
#include <hip/hip_runtime.h>
#include <math.h>

#define B_ 2
#define S_ 2048
#define D_ 1024
#define H_ 16
#define DK_ 64
#define EPS_ 1e-5f

typedef __bf16 bf16_t;
typedef __bf16 bf16x4 __attribute__((ext_vector_type(4)));
typedef __bf16 bf16x8 __attribute__((ext_vector_type(8)));
typedef float f32x4 __attribute__((ext_vector_type(4)));
typedef unsigned long long u64;
typedef unsigned short u16;

#define MFMA16(a, b, c) __builtin_amdgcn_mfma_f32_16x16x32_bf16(a, b, c, 0, 0, 0)

__device__ __forceinline__ void gload16(const bf16_t* g, bf16_t* l) {
    __builtin_amdgcn_global_load_lds(
        (const __attribute__((address_space(1))) void*)g,
        (__attribute__((address_space(3))) void*)l, 16, 0, 0);
}

// ---------------------------------------------------------------------------
// fp32 -> bf16 converters (8 elems/thread).
// ---------------------------------------------------------------------------
__global__ __launch_bounds__(256) void cvt3(const float* __restrict__ a,
        const float* __restrict__ b, const float* __restrict__ c,
        bf16_t* __restrict__ oa, bf16_t* __restrict__ ob, bf16_t* __restrict__ oc)
{
    int region = blockIdx.x >> 11;
    int i = ((blockIdx.x & 2047) << 8) + threadIdx.x;
    const float* in = (region == 0) ? a : (region == 1) ? b : c;
    bf16_t* out = (region == 0) ? oa : (region == 1) ? ob : oc;
    float4 v0 = reinterpret_cast<const float4*>(in)[i * 2];
    float4 v1 = reinterpret_cast<const float4*>(in)[i * 2 + 1];
    bf16x8 o = { (bf16_t)v0.x, (bf16_t)v0.y, (bf16_t)v0.z, (bf16_t)v0.w,
                 (bf16_t)v1.x, (bf16_t)v1.y, (bf16_t)v1.z, (bf16_t)v1.w };
    reinterpret_cast<bf16x8*>(out)[i] = o;
}

__global__ __launch_bounds__(256) void cvt4(const float* __restrict__ a,
        const float* __restrict__ b, const float* __restrict__ c, const float* __restrict__ d,
        bf16_t* __restrict__ oa, bf16_t* __restrict__ ob, bf16_t* __restrict__ oc,
        bf16_t* __restrict__ od)
{
    int region = blockIdx.x >> 9;
    int i = ((blockIdx.x & 511) << 8) + threadIdx.x;
    const float* in = (region == 0) ? a : (region == 1) ? b : (region == 2) ? c : d;
    bf16_t* out = (region == 0) ? oa : (region == 1) ? ob : (region == 2) ? oc : od;
    float4 v0 = reinterpret_cast<const float4*>(in)[i * 2];
    float4 v1 = reinterpret_cast<const float4*>(in)[i * 2 + 1];
    bf16x8 o = { (bf16_t)v0.x, (bf16_t)v0.y, (bf16_t)v0.z, (bf16_t)v0.w,
                 (bf16_t)v1.x, (bf16_t)v1.y, (bf16_t)v1.z, (bf16_t)v1.w };
    reinterpret_cast<bf16x8*>(out)[i] = o;
}

// ---------------------------------------------------------------------------
// Pack int32 mask [B,S,S] into per-(row,g) u16 streams.
// ---------------------------------------------------------------------------
__global__ __launch_bounds__(256) void mask_pack(const int* __restrict__ mask,
                                                 u16* __restrict__ bits2)
{
    size_t i = (size_t)blockIdx.x * 256 + threadIdx.x;
    int m = mask[i];
    u64 wm = __ballot(m != 0);
    if ((threadIdx.x & 63) == 0) {
        size_t widx = i >> 6;
        size_t row = widx >> 5;
        int t = (int)(widx & 31);
#pragma unroll
        for (int g = 0; g < 4; ++g) {
            u16 v = 0;
#pragma unroll
            for (int tk = 0; tk < 4; ++tk)
                v |= (u16)(((wm >> (tk * 16 + g * 4)) & 0xF) << (tk * 4));
            bits2[(row * 4 + g) * 32 + t] = v;
        }
    }
}

// ---------------------------------------------------------------------------
// 128x128-tile bf16 GEMM (unchanged from r9).
// ---------------------------------------------------------------------------
__global__ __launch_bounds__(256) void gemm_bf16(
        const bf16_t* __restrict__ X, const bf16_t* __restrict__ W,
        const float*  __restrict__ bias, const float* __restrict__ resid,
        float* __restrict__ xout, bf16_t* __restrict__ bout, int mode)
{
    __shared__ bf16_t As[128 * 64];
    __shared__ bf16_t Bs[128 * 64];
    const int tid = threadIdx.x;
    const int w = tid >> 6, l = tid & 63;
    const int c = l & 15, g = l >> 4;
    const int wr = w >> 1, wc = w & 1;
    const int m0 = blockIdx.y * 128, n0 = blockIdx.x * 128;

    const bf16_t* Asrc = (mode == 1) ? (W + (size_t)n0 * D_) : (X + (size_t)m0 * D_);
    const bf16_t* Bsrc = (mode == 1) ? (X + (size_t)m0 * D_) : (W + (size_t)n0 * D_);

    int srow[4], scol[4];
    uint32_t soff[4];
#pragma unroll
    for (int i = 0; i < 4; ++i) {
        int s = tid + i * 256;
        srow[i] = s >> 3;
        scol[i] = s & 7;
        soff[i] = (uint32_t)(s * 16) ^ (uint32_t)((srow[i] & 7) << 4);
    }

    bf16x8 areg[4], breg[4];
#pragma unroll
    for (int i = 0; i < 4; ++i) {
        areg[i] = *reinterpret_cast<const bf16x8*>(Asrc + (size_t)srow[i] * D_ + scol[i] * 8);
        breg[i] = *reinterpret_cast<const bf16x8*>(Bsrc + (size_t)srow[i] * D_ + scol[i] * 8);
    }

    f32x4 acc[4][4] = {};
    for (int kt = 0; kt < 16; ++kt) {
#pragma unroll
        for (int i = 0; i < 4; ++i) {
            *reinterpret_cast<bf16x8*>((char*)As + soff[i]) = areg[i];
            *reinterpret_cast<bf16x8*>((char*)Bs + soff[i]) = breg[i];
        }
        __syncthreads();
        if (kt + 1 < 16) {
            int k0 = (kt + 1) * 64;
#pragma unroll
            for (int i = 0; i < 4; ++i) {
                areg[i] = *reinterpret_cast<const bf16x8*>(Asrc + (size_t)srow[i] * D_ + k0 + scol[i] * 8);
                breg[i] = *reinterpret_cast<const bf16x8*>(Bsrc + (size_t)srow[i] * D_ + k0 + scol[i] * 8);
            }
        }
        bf16x8 bf0[4], bf1[4];
#pragma unroll
        for (int j = 0; j < 4; ++j) {
            int R = wc * 64 + j * 16 + c;
            const char* base = (const char*)Bs + R * 128;
            uint32_t msk = (uint32_t)((R & 7) << 4);
            bf0[j] = *reinterpret_cast<const bf16x8*>(base + ((g * 16) ^ msk));
            bf1[j] = *reinterpret_cast<const bf16x8*>(base + ((64 + g * 16) ^ msk));
        }
#pragma unroll
        for (int i = 0; i < 4; ++i) {
            int R = wr * 64 + i * 16 + c;
            const char* base = (const char*)As + R * 128;
            uint32_t msk = (uint32_t)((R & 7) << 4);
            bf16x8 a0 = *reinterpret_cast<const bf16x8*>(base + ((g * 16) ^ msk));
            bf16x8 a1 = *reinterpret_cast<const bf16x8*>(base + ((64 + g * 16) ^ msk));
#pragma unroll
            for (int j = 0; j < 4; ++j) {
                acc[i][j] = MFMA16(a0, bf0[j], acc[i][j]);
                acc[i][j] = MFMA16(a1, bf1[j], acc[i][j]);
            }
        }
        __syncthreads();
    }

#pragma unroll
    for (int i = 0; i < 4; ++i) {
#pragma unroll
        for (int j = 0; j < 4; ++j) {
#pragma unroll
            for (int r = 0; r < 4; ++r) {
                int P  = wr * 64 + i * 16 + g * 4 + r;
                int Qd = wc * 64 + j * 16 + c;
                float val = acc[i][j][r];
                if (mode == 2) {
                    int m = m0 + P, n = n0 + Qd;
                    xout[(size_t)m * D_ + n] = val + bias[n] + resid[(size_t)m * D_ + n];
                } else if (mode == 0) {
                    int m = m0 + P, n = n0 + Qd;
                    int bb = m >> 11, s = m & (S_ - 1);
                    int h = n >> 6, dk = n & 63;
                    bout[(((size_t)bb * H_ + h) * S_ + s) * DK_ + dk] = (bf16_t)(val + bias[n]);
                } else {
                    int n = n0 + P, m = m0 + Qd;
                    int bb = m >> 11, s = m & (S_ - 1);
                    int h = n >> 6, dk = n & 63;
                    bout[(((size_t)bb * H_ + h) * DK_ + dk) * S_ + s] = (bf16_t)(val + bias[n]);
                }
            }
        }
    }
}

// ---------------------------------------------------------------------------
// Fused attention: no-max softmax. K/V via global_load_lds, 3-deep buffers,
// counted vmcnt (T4). P routed through fp32 LDS tile (Pf, XOR-swizzled) and
// read back LINEARLY so attn stores are 4x256B segments per instruction
// (full cache lines) instead of 16x64B. MFMA A-operand derived from Pf.
// ---------------------------------------------------------------------------
__global__ __launch_bounds__(512) void fused_attn(
        const bf16_t* __restrict__ qh,   // [B,H,S,DK]
        const bf16_t* __restrict__ kh,   // [B,H,S,DK]
        const bf16_t* __restrict__ vt,   // [B,H,DK,S]
        const u16*    __restrict__ bits2,// [B*S*4][32] u16
        float* __restrict__ attn,        // [B,H,S,S]
        bf16_t* __restrict__ ctx)        // [B,S,D] bf16
{
    constexpr int TILE = 64;
    constexpr int NT = S_ / TILE;        // 32
    __shared__ bf16_t Kbuf[3][TILE * DK_];   // 3 x 8 KB
    __shared__ bf16_t Vbuf[3][TILE * DK_];   // 3 x 8 KB
    __shared__ float  Pf[8][16 * 64];        // 32 KB, 4 KB per wave

    const int tid = threadIdx.x;
    const int w = tid >> 6, l = tid & 63;
    const int c = l & 15, g = l >> 4;

    const int id = blockIdx.x;
    const int xcd = id & 7, ixd = id >> 3;
    const int bh = xcd * 4 + (ixd >> 4);
    const int qt = ixd & 15;
    const int q0 = qt * 128 + w * 16;
    const int b = bh >> 4, h = bh & 15;

    const bf16_t* Q = qh + ((size_t)bh * S_ + q0) * DK_;
    const bf16_t* K = kh + (size_t)bh * S_ * DK_;
    const bf16_t* V = vt + (size_t)bh * DK_ * S_;
    float* Astrip = attn + ((size_t)bh * S_ + q0) * S_;   // wave's 16-row strip

    // mask record: 64 B per lane, all 32 tiles
    u64 mreg[8];
    {
        const u64* mp = reinterpret_cast<const u64*>(
            bits2 + (((size_t)b * S_ + q0 + c) * 4 + g) * 32);
#pragma unroll
        for (int i = 0; i < 8; ++i) mreg[i] = mp[i];
    }

    bf16x8 qf0 = *reinterpret_cast<const bf16x8*>(&Q[c * DK_ + g * 8]);
    bf16x8 qf1 = *reinterpret_cast<const bf16x8*>(&Q[c * DK_ + 32 + g * 8]);

    // DMA staging: wave w owns LDS slots [w*64, w*64+64). Global source
    // pre-swizzled (involution), read side XORs the same mask.
    const int row_s = (w << 3) + (l >> 3);
    const int csx = (l & 7) ^ (row_s & 7);
    const bf16_t* Kg = K + (size_t)row_s * DK_ + csx * 8;
    const bf16_t* Vg = V + (size_t)row_s * S_ + csx * 8;
    const int woffu = __builtin_amdgcn_readfirstlane(w * 512);
    const uint32_t rm = (uint32_t)((c & 7) << 4);   // K/V read XOR
    const uint32_t xr = (uint32_t)((c & 7) << 4);   // Pf row-c XOR

    //================= pass 1: row sums of exp =================
    gload16(Kg, &Kbuf[0][woffu]);
    gload16(Kg + (size_t)TILE * DK_, &Kbuf[1][woffu]);
    asm volatile("s_waitcnt vmcnt(1)" ::: "memory");
    __builtin_amdgcn_s_barrier();

    float l_r = 0.f;
    int bc = 0;
    for (int t = 0; t < NT; ++t) {
        if (t + 2 < NT) {
            int b2 = bc + 2; if (b2 >= 3) b2 -= 3;
            gload16(Kg + (size_t)(t + 2) * TILE * DK_, &Kbuf[b2][woffu]);
        }
        __builtin_amdgcn_sched_barrier(0);
        u16 m16 = (u16)(mreg[t >> 2] >> ((t & 3) << 4));
        const char* kb = (const char*)&Kbuf[bc][0];
        f32x4 acc[4] = {};
        __builtin_amdgcn_s_setprio(1);
#pragma unroll
        for (int tk = 0; tk < 4; ++tk) {
            uint32_t base = (uint32_t)((tk * 16 + c) * 128 + g * 16);
            bf16x8 a0 = *reinterpret_cast<const bf16x8*>(kb + (base ^ rm));
            bf16x8 a1 = *reinterpret_cast<const bf16x8*>(kb + ((base + 64) ^ rm));
            acc[tk] = MFMA16(a0, qf0, acc[tk]);
            acc[tk] = MFMA16(a1, qf1, acc[tk]);
        }
        __builtin_amdgcn_s_setprio(0);
        float ps = 0.f;
#pragma unroll
        for (int tk = 0; tk < 4; ++tk) {
#pragma unroll
            for (int r = 0; r < 4; ++r) {
                float e = __expf(acc[tk][r] * 0.125f);
                e = ((m16 >> (tk * 4 + r)) & 1) ? e : 0.f;
                ps += e;
            }
        }
        l_r += ps;
        if (t + 2 < NT) asm volatile("s_waitcnt vmcnt(1)" ::: "memory");
        else            asm volatile("s_waitcnt vmcnt(0)" ::: "memory");
        asm volatile("s_waitcnt lgkmcnt(0)" ::: "memory");
        __builtin_amdgcn_sched_barrier(0);
        __builtin_amdgcn_s_barrier();
        bc = (bc == 2) ? 0 : bc + 1;
    }
    l_r += __shfl_xor(l_r, 16);
    l_r += __shfl_xor(l_r, 32);
    const float inv_l = 1.0f / l_r;

    //================= pass 2: emit P + PV =================
    gload16(Kg, &Kbuf[0][woffu]);
    gload16(Vg, &Vbuf[0][woffu]);
    gload16(Kg + (size_t)TILE * DK_, &Kbuf[1][woffu]);
    gload16(Vg + TILE, &Vbuf[1][woffu]);
    asm volatile("s_waitcnt vmcnt(2)" ::: "memory");
    __builtin_amdgcn_s_barrier();

    float* pf = &Pf[w][0];
    f32x4 oacc[4] = {};
    bc = 0;
    for (int t = 0; t < NT; ++t) {
        if (t + 2 < NT) {
            int b2 = bc + 2; if (b2 >= 3) b2 -= 3;
            gload16(Kg + (size_t)(t + 2) * TILE * DK_, &Kbuf[b2][woffu]);
            gload16(Vg + (t + 2) * TILE, &Vbuf[b2][woffu]);
        }
        __builtin_amdgcn_sched_barrier(0);
        u16 m16 = (u16)(mreg[t >> 2] >> ((t & 3) << 4));
        const char* kb = (const char*)&Kbuf[bc][0];
        const char* vb = (const char*)&Vbuf[bc][0];
        f32x4 acc[4] = {};
        __builtin_amdgcn_s_setprio(1);
#pragma unroll
        for (int tk = 0; tk < 4; ++tk) {
            uint32_t base = (uint32_t)((tk * 16 + c) * 128 + g * 16);
            bf16x8 a0 = *reinterpret_cast<const bf16x8*>(kb + (base ^ rm));
            bf16x8 a1 = *reinterpret_cast<const bf16x8*>(kb + ((base + 64) ^ rm));
            acc[tk] = MFMA16(a0, qf0, acc[tk]);
            acc[tk] = MFMA16(a1, qf1, acc[tk]);
        }
        __builtin_amdgcn_s_setprio(0);
        // p = exp * inv_l (masked); stage fp32 P into Pf (row c, XOR-swizzled)
#pragma unroll
        for (int tk = 0; tk < 4; ++tk) {
            f32x4 pv;
#pragma unroll
            for (int r = 0; r < 4; ++r) {
                float p = __expf(acc[tk][r] * 0.125f) * inv_l;
                pv[r] = ((m16 >> (tk * 4 + r)) & 1) ? p : 0.f;
            }
            *reinterpret_cast<f32x4*>((char*)pf + ((uint32_t)(c * 256 + tk * 64 + g * 16) ^ xr)) = pv;
        }
        asm volatile("s_waitcnt lgkmcnt(0)" ::: "memory");
        __builtin_amdgcn_sched_barrier(0);
        // linear read-back -> contiguous 256B-segment stores to attn
#pragma unroll
        for (int i = 0; i < 4; ++i) {
            int row = i * 4 + (l >> 4);
            uint32_t off = (uint32_t)(i * 1024 + l * 16) ^ (uint32_t)((row & 7) << 4);
            f32x4 sv = *reinterpret_cast<const f32x4*>((char*)pf + off);
            *reinterpret_cast<f32x4*>(Astrip + (size_t)row * S_ + t * TILE + (l & 15) * 4) = sv;
        }
        // MFMA A-operand from Pf (row c): keys [g*8,+8) and [32+g*8,+8)
        f32x4 p0a = *reinterpret_cast<const f32x4*>((char*)pf + ((uint32_t)(c * 256 + g * 32) ^ xr));
        f32x4 p0b = *reinterpret_cast<const f32x4*>((char*)pf + ((uint32_t)(c * 256 + g * 32 + 16) ^ xr));
        f32x4 p1a = *reinterpret_cast<const f32x4*>((char*)pf + ((uint32_t)(c * 256 + 128 + g * 32) ^ xr));
        f32x4 p1b = *reinterpret_cast<const f32x4*>((char*)pf + ((uint32_t)(c * 256 + 128 + g * 32 + 16) ^ xr));
        bf16x8 pa0 = { (bf16_t)p0a[0], (bf16_t)p0a[1], (bf16_t)p0a[2], (bf16_t)p0a[3],
                       (bf16_t)p0b[0], (bf16_t)p0b[1], (bf16_t)p0b[2], (bf16_t)p0b[3] };
        bf16x8 pa1 = { (bf16_t)p1a[0], (bf16_t)p1a[1], (bf16_t)p1a[2], (bf16_t)p1a[3],
                       (bf16_t)p1b[0], (bf16_t)p1b[1], (bf16_t)p1b[2], (bf16_t)p1b[3] };
        __builtin_amdgcn_s_setprio(1);
#pragma unroll
        for (int tk = 0; tk < 4; ++tk) {
            uint32_t base = (uint32_t)((tk * 16 + c) * 128 + g * 16);
            bf16x8 b0 = *reinterpret_cast<const bf16x8*>(vb + (base ^ rm));
            bf16x8 b1 = *reinterpret_cast<const bf16x8*>(vb + ((base + 64) ^ rm));
            oacc[tk] = MFMA16(pa0, b0, oacc[tk]);
            oacc[tk] = MFMA16(pa1, b1, oacc[tk]);
        }
        __builtin_amdgcn_s_setprio(0);
        // counted drain (T4): need DMA(t+1) retired; newer ops = S(t-1)res +
        // DMA(t+2)2 + S(t)4 -> vmcnt(6) general, vmcnt(4) at t==NT-2.
        if (t + 2 < NT)       asm volatile("s_waitcnt vmcnt(6)" ::: "memory");
        else if (t + 1 < NT)  asm volatile("s_waitcnt vmcnt(4)" ::: "memory");
        asm volatile("s_waitcnt lgkmcnt(0)" ::: "memory");
        __builtin_amdgcn_sched_barrier(0);
        __builtin_amdgcn_s_barrier();
        bc = (bc == 2) ? 0 : bc + 1;
    }

#pragma unroll
    for (int tk = 0; tk < 4; ++tk) {
#pragma unroll
        for (int r = 0; r < 4; ++r) {
            int q = q0 + g * 4 + r;
            ctx[((size_t)b * S_ + q) * D_ + h * DK_ + tk * 16 + c] = (bf16_t)oacc[tk][r];
        }
    }
}

// ---------------------------------------------------------------------------
// LayerNorm over last dim (1024), 4096 rows
// ---------------------------------------------------------------------------
__global__ void ln_kernel(const float* __restrict__ x, const float* __restrict__ gamma,
                          const float* __restrict__ beta, float* __restrict__ out)
{
    int row = blockIdx.x;
    const float* xr = x + (size_t)row * D_;
    int tid = threadIdx.x;
    float v[4];
    float s = 0.f;
#pragma unroll
    for (int i = 0; i < 4; ++i) {
        v[i] = xr[tid + i * 256];
        s += v[i];
    }
#pragma unroll
    for (int off = 32; off > 0; off >>= 1) s += __shfl_xor(s, off);
    __shared__ float red[4];
    int wid = tid >> 6, lane = tid & 63;
    if (lane == 0) red[wid] = s;
    __syncthreads();
    float mu = (red[0] + red[1] + red[2] + red[3]) * (1.0f / D_);
    float vs = 0.f;
#pragma unroll
    for (int i = 0; i < 4; ++i) {
        float d = v[i] - mu;
        vs += d * d;
    }
#pragma unroll
    for (int off = 32; off > 0; off >>= 1) vs += __shfl_xor(vs, off);
    __syncthreads();
    __shared__ float red2[4];
    if (lane == 0) red2[wid] = vs;
    __syncthreads();
    float var = (red2[0] + red2[1] + red2[2] + red2[3]) * (1.0f / D_);
    float rs = rsqrtf(var + EPS_);
#pragma unroll
    for (int i = 0; i < 4; ++i) {
        int c = tid + i * 256;
        out[(size_t)row * D_ + c] = (v[i] - mu) * rs * gamma[c] + beta[c];
    }
}

extern "C" void kernel_launch(void* const* d_in, const int* in_sizes, int n_in,
                              void* d_out, int out_size, void* d_ws, size_t ws_size,
                              hipStream_t stream) {
    const float* q    = (const float*)d_in[0];
    const float* k    = (const float*)d_in[1];
    const float* v    = (const float*)d_in[2];
    const int*   mask = (const int*)d_in[3];
    const float* Wq   = (const float*)d_in[4];
    const float* bq   = (const float*)d_in[5];
    const float* Wk   = (const float*)d_in[6];
    const float* bk   = (const float*)d_in[7];
    const float* Wv   = (const float*)d_in[8];
    const float* bv   = (const float*)d_in[9];
    const float* Wo   = (const float*)d_in[10];
    const float* bo   = (const float*)d_in[11];
    const float* gamma= (const float*)d_in[12];
    const float* beta = (const float*)d_in[13];

    float* out  = (float*)d_out;                       // [B,S,D]
    float* attn = out + (size_t)B_ * S_ * D_;          // [B,H,S,S]

    uint8_t* ws = (uint8_t*)d_ws;
    bf16_t* xq  = (bf16_t*)(ws);
    bf16_t* xk  = (bf16_t*)(ws + ((size_t)8  << 20));
    bf16_t* xv  = (bf16_t*)(ws + ((size_t)16 << 20));
    bf16_t* wqb = (bf16_t*)(ws + ((size_t)24 << 20));
    bf16_t* wkb = (bf16_t*)(ws + ((size_t)26 << 20));
    bf16_t* wvb = (bf16_t*)(ws + ((size_t)28 << 20));
    bf16_t* wob = (bf16_t*)(ws + ((size_t)30 << 20));
    bf16_t* qh  = (bf16_t*)(ws + ((size_t)32 << 20));
    u16*    bits= (u16*)   (ws + ((size_t)40 << 20));
    bf16_t* kh  = (bf16_t*)(ws);                       // over xq
    bf16_t* vt  = (bf16_t*)(ws + ((size_t)8  << 20));  // over xk
    bf16_t* ctx = (bf16_t*)(ws + ((size_t)16 << 20));  // over xv
    float*  x   = (float*) (ws + ((size_t)32 << 20));  // over qh+bits

    dim3 blk(256);
    cvt3<<<dim3(6144), blk, 0, stream>>>(q, k, v, xq, xk, xv);
    cvt4<<<dim3(2048), blk, 0, stream>>>(Wq, Wk, Wv, Wo, wqb, wkb, wvb, wob);
    mask_pack<<<dim3((B_ * S_ * S_) / 256), blk, 0, stream>>>(mask, bits);

    dim3 ggemm(D_ / 128, (B_ * S_) / 128);             // (8, 32)
    gemm_bf16<<<ggemm, blk, 0, stream>>>(xq, wqb, bq, nullptr, nullptr, qh, 0);
    gemm_bf16<<<ggemm, blk, 0, stream>>>(xk, wkb, bk, nullptr, nullptr, kh, 0);
    gemm_bf16<<<ggemm, blk, 0, stream>>>(xv, wvb, bv, nullptr, nullptr, vt, 1);

    fused_attn<<<dim3(512), dim3(512), 0, stream>>>(qh, kh, vt, bits, attn, ctx);

    gemm_bf16<<<ggemm, blk, 0, stream>>>(ctx, wob, bo, q, x, nullptr, 2);
    ln_kernel<<<dim3(B_ * S_), blk, 0, stream>>>(x, gamma, beta, out);
}

// Round 12
// 268.683 us; speedup vs baseline: 1.4080x; 1.3592x over previous
//
#include <hip/hip_runtime.h>
#include <math.h>

#define B_ 2
#define S_ 2048
#define D_ 1024
#define H_ 16
#define DK_ 64
#define EPS_ 1e-5f

typedef __bf16 bf16_t;
typedef __bf16 bf16x4 __attribute__((ext_vector_type(4)));
typedef __bf16 bf16x8 __attribute__((ext_vector_type(8)));
typedef float f32x4 __attribute__((ext_vector_type(4)));
typedef unsigned long long u64;
typedef unsigned short u16;

#define MFMA16(a, b, c) __builtin_amdgcn_mfma_f32_16x16x32_bf16(a, b, c, 0, 0, 0)

__device__ __forceinline__ void gload16(const bf16_t* g, bf16_t* l) {
    __builtin_amdgcn_global_load_lds(
        (const __attribute__((address_space(1))) void*)g,
        (__attribute__((address_space(3))) void*)l, 16, 0, 0);
}

// ---------------------------------------------------------------------------
// fp32 -> bf16 converters (8 elems/thread).
// ---------------------------------------------------------------------------
__global__ __launch_bounds__(256) void cvt3(const float* __restrict__ a,
        const float* __restrict__ b, const float* __restrict__ c,
        bf16_t* __restrict__ oa, bf16_t* __restrict__ ob, bf16_t* __restrict__ oc)
{
    int region = blockIdx.x >> 11;
    int i = ((blockIdx.x & 2047) << 8) + threadIdx.x;
    const float* in = (region == 0) ? a : (region == 1) ? b : c;
    bf16_t* out = (region == 0) ? oa : (region == 1) ? ob : oc;
    float4 v0 = reinterpret_cast<const float4*>(in)[i * 2];
    float4 v1 = reinterpret_cast<const float4*>(in)[i * 2 + 1];
    bf16x8 o = { (bf16_t)v0.x, (bf16_t)v0.y, (bf16_t)v0.z, (bf16_t)v0.w,
                 (bf16_t)v1.x, (bf16_t)v1.y, (bf16_t)v1.z, (bf16_t)v1.w };
    reinterpret_cast<bf16x8*>(out)[i] = o;
}

__global__ __launch_bounds__(256) void cvt4(const float* __restrict__ a,
        const float* __restrict__ b, const float* __restrict__ c, const float* __restrict__ d,
        bf16_t* __restrict__ oa, bf16_t* __restrict__ ob, bf16_t* __restrict__ oc,
        bf16_t* __restrict__ od)
{
    int region = blockIdx.x >> 9;
    int i = ((blockIdx.x & 511) << 8) + threadIdx.x;
    const float* in = (region == 0) ? a : (region == 1) ? b : (region == 2) ? c : d;
    bf16_t* out = (region == 0) ? oa : (region == 1) ? ob : (region == 2) ? oc : od;
    float4 v0 = reinterpret_cast<const float4*>(in)[i * 2];
    float4 v1 = reinterpret_cast<const float4*>(in)[i * 2 + 1];
    bf16x8 o = { (bf16_t)v0.x, (bf16_t)v0.y, (bf16_t)v0.z, (bf16_t)v0.w,
                 (bf16_t)v1.x, (bf16_t)v1.y, (bf16_t)v1.z, (bf16_t)v1.w };
    reinterpret_cast<bf16x8*>(out)[i] = o;
}

// ---------------------------------------------------------------------------
// Pack int32 mask [B,S,S] into per-(row,g) u16 streams.
// ---------------------------------------------------------------------------
__global__ __launch_bounds__(256) void mask_pack(const int* __restrict__ mask,
                                                 u16* __restrict__ bits2)
{
    size_t i = (size_t)blockIdx.x * 256 + threadIdx.x;
    int m = mask[i];
    u64 wm = __ballot(m != 0);
    if ((threadIdx.x & 63) == 0) {
        size_t widx = i >> 6;
        size_t row = widx >> 5;
        int t = (int)(widx & 31);
#pragma unroll
        for (int g = 0; g < 4; ++g) {
            u16 v = 0;
#pragma unroll
            for (int tk = 0; tk < 4; ++tk)
                v |= (u16)(((wm >> (tk * 16 + g * 4)) & 0xF) << (tk * 4));
            bits2[(row * 4 + g) * 32 + t] = v;
        }
    }
}

// ---------------------------------------------------------------------------
// Shared 128x128 GEMM body. mode 0: bf16 head-split out; mode 1: bf16
// transposed out (operands swapped by caller); mode 2: fp32 + bias + resid.
// ---------------------------------------------------------------------------
__device__ __forceinline__ void gemm_body(
        const bf16_t* __restrict__ Asrc, const bf16_t* __restrict__ Bsrc,
        const float* __restrict__ bias, const float* __restrict__ resid,
        float* __restrict__ xout, bf16_t* __restrict__ bout,
        int mode, int m0, int n0)
{
    __shared__ bf16_t As[128 * 64];
    __shared__ bf16_t Bs[128 * 64];
    const int tid = threadIdx.x;
    const int w = tid >> 6, l = tid & 63;
    const int c = l & 15, g = l >> 4;
    const int wr = w >> 1, wc = w & 1;

    int srow[4], scol[4];
    uint32_t soff[4];
#pragma unroll
    for (int i = 0; i < 4; ++i) {
        int s = tid + i * 256;
        srow[i] = s >> 3;
        scol[i] = s & 7;
        soff[i] = (uint32_t)(s * 16) ^ (uint32_t)((srow[i] & 7) << 4);
    }

    bf16x8 areg[4], breg[4];
#pragma unroll
    for (int i = 0; i < 4; ++i) {
        areg[i] = *reinterpret_cast<const bf16x8*>(Asrc + (size_t)srow[i] * D_ + scol[i] * 8);
        breg[i] = *reinterpret_cast<const bf16x8*>(Bsrc + (size_t)srow[i] * D_ + scol[i] * 8);
    }

    f32x4 acc[4][4] = {};
    for (int kt = 0; kt < 16; ++kt) {
#pragma unroll
        for (int i = 0; i < 4; ++i) {
            *reinterpret_cast<bf16x8*>((char*)As + soff[i]) = areg[i];
            *reinterpret_cast<bf16x8*>((char*)Bs + soff[i]) = breg[i];
        }
        __syncthreads();
        if (kt + 1 < 16) {
            int k0 = (kt + 1) * 64;
#pragma unroll
            for (int i = 0; i < 4; ++i) {
                areg[i] = *reinterpret_cast<const bf16x8*>(Asrc + (size_t)srow[i] * D_ + k0 + scol[i] * 8);
                breg[i] = *reinterpret_cast<const bf16x8*>(Bsrc + (size_t)srow[i] * D_ + k0 + scol[i] * 8);
            }
        }
        bf16x8 bf0[4], bf1[4];
#pragma unroll
        for (int j = 0; j < 4; ++j) {
            int R = wc * 64 + j * 16 + c;
            const char* base = (const char*)Bs + R * 128;
            uint32_t msk = (uint32_t)((R & 7) << 4);
            bf0[j] = *reinterpret_cast<const bf16x8*>(base + ((g * 16) ^ msk));
            bf1[j] = *reinterpret_cast<const bf16x8*>(base + ((64 + g * 16) ^ msk));
        }
#pragma unroll
        for (int i = 0; i < 4; ++i) {
            int R = wr * 64 + i * 16 + c;
            const char* base = (const char*)As + R * 128;
            uint32_t msk = (uint32_t)((R & 7) << 4);
            bf16x8 a0 = *reinterpret_cast<const bf16x8*>(base + ((g * 16) ^ msk));
            bf16x8 a1 = *reinterpret_cast<const bf16x8*>(base + ((64 + g * 16) ^ msk));
#pragma unroll
            for (int j = 0; j < 4; ++j) {
                acc[i][j] = MFMA16(a0, bf0[j], acc[i][j]);
                acc[i][j] = MFMA16(a1, bf1[j], acc[i][j]);
            }
        }
        __syncthreads();
    }

#pragma unroll
    for (int i = 0; i < 4; ++i) {
#pragma unroll
        for (int j = 0; j < 4; ++j) {
#pragma unroll
            for (int r = 0; r < 4; ++r) {
                int P  = wr * 64 + i * 16 + g * 4 + r;
                int Qd = wc * 64 + j * 16 + c;
                float val = acc[i][j][r];
                if (mode == 2) {
                    int m = m0 + P, n = n0 + Qd;
                    xout[(size_t)m * D_ + n] = val + bias[n] + resid[(size_t)m * D_ + n];
                } else if (mode == 0) {
                    int m = m0 + P, n = n0 + Qd;
                    int bb = m >> 11, s = m & (S_ - 1);
                    int h = n >> 6, dk = n & 63;
                    bout[(((size_t)bb * H_ + h) * S_ + s) * DK_ + dk] = (bf16_t)(val + bias[n]);
                } else {
                    int n = n0 + P, m = m0 + Qd;
                    int bb = m >> 11, s = m & (S_ - 1);
                    int h = n >> 6, dk = n & 63;
                    bout[(((size_t)bb * H_ + h) * DK_ + dk) * S_ + s] = (bf16_t)(val + bias[n]);
                }
            }
        }
    }
}

// Fused QKV projection: blockIdx.z selects tensor (0=q,1=k,2=v). 768 blocks.
__global__ __launch_bounds__(256) void qkv_gemm(
        const bf16_t* __restrict__ xq, const bf16_t* __restrict__ xk,
        const bf16_t* __restrict__ xv,
        const bf16_t* __restrict__ wq, const bf16_t* __restrict__ wk,
        const bf16_t* __restrict__ wv,
        const float* __restrict__ bq, const float* __restrict__ bk,
        const float* __restrict__ bv,
        bf16_t* __restrict__ qh, bf16_t* __restrict__ kh, bf16_t* __restrict__ vt)
{
    const int z = blockIdx.z;
    const int m0 = blockIdx.y * 128, n0 = blockIdx.x * 128;
    const bf16_t* X = (z == 0) ? xq : (z == 1) ? xk : xv;
    const bf16_t* W = (z == 0) ? wq : (z == 1) ? wk : wv;
    const float* bias = (z == 0) ? bq : (z == 1) ? bk : bv;
    bf16_t* out = (z == 0) ? qh : (z == 1) ? kh : vt;
    int mode = (z == 2) ? 1 : 0;
    const bf16_t* Asrc = (mode == 1) ? (W + (size_t)n0 * D_) : (X + (size_t)m0 * D_);
    const bf16_t* Bsrc = (mode == 1) ? (X + (size_t)m0 * D_) : (W + (size_t)n0 * D_);
    gemm_body(Asrc, Bsrc, bias, nullptr, nullptr, out, mode, m0, n0);
}

// Output projection + bias + residual (mode 2).
__global__ __launch_bounds__(256) void oproj_gemm(
        const bf16_t* __restrict__ ctx, const bf16_t* __restrict__ wo,
        const float* __restrict__ bo, const float* __restrict__ resid,
        float* __restrict__ x)
{
    const int m0 = blockIdx.y * 128, n0 = blockIdx.x * 128;
    gemm_body(ctx + (size_t)m0 * D_, wo + (size_t)n0 * D_, bo, resid, x, nullptr, 2, m0, n0);
}

// ---------------------------------------------------------------------------
// Fused attention: as r11 (DMA staging, 3-deep, counted vmcnt, Pf coalesce)
// but attn stores are NONTEMPORAL (no L2 allocation for the 536 MB stream).
// ---------------------------------------------------------------------------
__global__ __launch_bounds__(512) void fused_attn(
        const bf16_t* __restrict__ qh,   // [B,H,S,DK]
        const bf16_t* __restrict__ kh,   // [B,H,S,DK]
        const bf16_t* __restrict__ vt,   // [B,H,DK,S]
        const u16*    __restrict__ bits2,// [B*S*4][32] u16
        float* __restrict__ attn,        // [B,H,S,S]
        bf16_t* __restrict__ ctx)        // [B,S,D] bf16
{
    constexpr int TILE = 64;
    constexpr int NT = S_ / TILE;        // 32
    __shared__ bf16_t Kbuf[3][TILE * DK_];
    __shared__ bf16_t Vbuf[3][TILE * DK_];
    __shared__ float  Pf[8][16 * 64];

    const int tid = threadIdx.x;
    const int w = tid >> 6, l = tid & 63;
    const int c = l & 15, g = l >> 4;

    const int id = blockIdx.x;
    const int xcd = id & 7, ixd = id >> 3;
    const int bh = xcd * 4 + (ixd >> 4);
    const int qt = ixd & 15;
    const int q0 = qt * 128 + w * 16;
    const int b = bh >> 4, h = bh & 15;

    const bf16_t* Q = qh + ((size_t)bh * S_ + q0) * DK_;
    const bf16_t* K = kh + (size_t)bh * S_ * DK_;
    const bf16_t* V = vt + (size_t)bh * DK_ * S_;
    float* Astrip = attn + ((size_t)bh * S_ + q0) * S_;

    u64 mreg[8];
    {
        const u64* mp = reinterpret_cast<const u64*>(
            bits2 + (((size_t)b * S_ + q0 + c) * 4 + g) * 32);
#pragma unroll
        for (int i = 0; i < 8; ++i) mreg[i] = mp[i];
    }

    bf16x8 qf0 = *reinterpret_cast<const bf16x8*>(&Q[c * DK_ + g * 8]);
    bf16x8 qf1 = *reinterpret_cast<const bf16x8*>(&Q[c * DK_ + 32 + g * 8]);

    const int row_s = (w << 3) + (l >> 3);
    const int csx = (l & 7) ^ (row_s & 7);
    const bf16_t* Kg = K + (size_t)row_s * DK_ + csx * 8;
    const bf16_t* Vg = V + (size_t)row_s * S_ + csx * 8;
    const int woffu = __builtin_amdgcn_readfirstlane(w * 512);
    const uint32_t rm = (uint32_t)((c & 7) << 4);
    const uint32_t xr = (uint32_t)((c & 7) << 4);

    //================= pass 1: row sums of exp =================
    gload16(Kg, &Kbuf[0][woffu]);
    gload16(Kg + (size_t)TILE * DK_, &Kbuf[1][woffu]);
    asm volatile("s_waitcnt vmcnt(1)" ::: "memory");
    __builtin_amdgcn_s_barrier();

    float l_r = 0.f;
    int bc = 0;
    for (int t = 0; t < NT; ++t) {
        if (t + 2 < NT) {
            int b2 = bc + 2; if (b2 >= 3) b2 -= 3;
            gload16(Kg + (size_t)(t + 2) * TILE * DK_, &Kbuf[b2][woffu]);
        }
        __builtin_amdgcn_sched_barrier(0);
        u16 m16 = (u16)(mreg[t >> 2] >> ((t & 3) << 4));
        const char* kb = (const char*)&Kbuf[bc][0];
        f32x4 acc[4] = {};
        __builtin_amdgcn_s_setprio(1);
#pragma unroll
        for (int tk = 0; tk < 4; ++tk) {
            uint32_t base = (uint32_t)((tk * 16 + c) * 128 + g * 16);
            bf16x8 a0 = *reinterpret_cast<const bf16x8*>(kb + (base ^ rm));
            bf16x8 a1 = *reinterpret_cast<const bf16x8*>(kb + ((base + 64) ^ rm));
            acc[tk] = MFMA16(a0, qf0, acc[tk]);
            acc[tk] = MFMA16(a1, qf1, acc[tk]);
        }
        __builtin_amdgcn_s_setprio(0);
        float ps = 0.f;
#pragma unroll
        for (int tk = 0; tk < 4; ++tk) {
#pragma unroll
            for (int r = 0; r < 4; ++r) {
                float e = __expf(acc[tk][r] * 0.125f);
                e = ((m16 >> (tk * 4 + r)) & 1) ? e : 0.f;
                ps += e;
            }
        }
        l_r += ps;
        if (t + 2 < NT) asm volatile("s_waitcnt vmcnt(1)" ::: "memory");
        else            asm volatile("s_waitcnt vmcnt(0)" ::: "memory");
        asm volatile("s_waitcnt lgkmcnt(0)" ::: "memory");
        __builtin_amdgcn_sched_barrier(0);
        __builtin_amdgcn_s_barrier();
        bc = (bc == 2) ? 0 : bc + 1;
    }
    l_r += __shfl_xor(l_r, 16);
    l_r += __shfl_xor(l_r, 32);
    const float inv_l = 1.0f / l_r;

    //================= pass 2: emit P + PV =================
    gload16(Kg, &Kbuf[0][woffu]);
    gload16(Vg, &Vbuf[0][woffu]);
    gload16(Kg + (size_t)TILE * DK_, &Kbuf[1][woffu]);
    gload16(Vg + TILE, &Vbuf[1][woffu]);
    asm volatile("s_waitcnt vmcnt(2)" ::: "memory");
    __builtin_amdgcn_s_barrier();

    float* pf = &Pf[w][0];
    f32x4 oacc[4] = {};
    bc = 0;
    for (int t = 0; t < NT; ++t) {
        if (t + 2 < NT) {
            int b2 = bc + 2; if (b2 >= 3) b2 -= 3;
            gload16(Kg + (size_t)(t + 2) * TILE * DK_, &Kbuf[b2][woffu]);
            gload16(Vg + (t + 2) * TILE, &Vbuf[b2][woffu]);
        }
        __builtin_amdgcn_sched_barrier(0);
        u16 m16 = (u16)(mreg[t >> 2] >> ((t & 3) << 4));
        const char* kb = (const char*)&Kbuf[bc][0];
        const char* vb = (const char*)&Vbuf[bc][0];
        f32x4 acc[4] = {};
        __builtin_amdgcn_s_setprio(1);
#pragma unroll
        for (int tk = 0; tk < 4; ++tk) {
            uint32_t base = (uint32_t)((tk * 16 + c) * 128 + g * 16);
            bf16x8 a0 = *reinterpret_cast<const bf16x8*>(kb + (base ^ rm));
            bf16x8 a1 = *reinterpret_cast<const bf16x8*>(kb + ((base + 64) ^ rm));
            acc[tk] = MFMA16(a0, qf0, acc[tk]);
            acc[tk] = MFMA16(a1, qf1, acc[tk]);
        }
        __builtin_amdgcn_s_setprio(0);
#pragma unroll
        for (int tk = 0; tk < 4; ++tk) {
            f32x4 pv;
#pragma unroll
            for (int r = 0; r < 4; ++r) {
                float p = __expf(acc[tk][r] * 0.125f) * inv_l;
                pv[r] = ((m16 >> (tk * 4 + r)) & 1) ? p : 0.f;
            }
            *reinterpret_cast<f32x4*>((char*)pf + ((uint32_t)(c * 256 + tk * 64 + g * 16) ^ xr)) = pv;
        }
        asm volatile("s_waitcnt lgkmcnt(0)" ::: "memory");
        __builtin_amdgcn_sched_barrier(0);
        // linear read-back -> NONTEMPORAL contiguous stores (no L2 alloc)
#pragma unroll
        for (int i = 0; i < 4; ++i) {
            int row = i * 4 + (l >> 4);
            uint32_t off = (uint32_t)(i * 1024 + l * 16) ^ (uint32_t)((row & 7) << 4);
            f32x4 sv = *reinterpret_cast<const f32x4*>((char*)pf + off);
            __builtin_nontemporal_store(sv,
                reinterpret_cast<f32x4*>(Astrip + (size_t)row * S_ + t * TILE + (l & 15) * 4));
        }
        f32x4 p0a = *reinterpret_cast<const f32x4*>((char*)pf + ((uint32_t)(c * 256 + g * 32) ^ xr));
        f32x4 p0b = *reinterpret_cast<const f32x4*>((char*)pf + ((uint32_t)(c * 256 + g * 32 + 16) ^ xr));
        f32x4 p1a = *reinterpret_cast<const f32x4*>((char*)pf + ((uint32_t)(c * 256 + 128 + g * 32) ^ xr));
        f32x4 p1b = *reinterpret_cast<const f32x4*>((char*)pf + ((uint32_t)(c * 256 + 128 + g * 32 + 16) ^ xr));
        bf16x8 pa0 = { (bf16_t)p0a[0], (bf16_t)p0a[1], (bf16_t)p0a[2], (bf16_t)p0a[3],
                       (bf16_t)p0b[0], (bf16_t)p0b[1], (bf16_t)p0b[2], (bf16_t)p0b[3] };
        bf16x8 pa1 = { (bf16_t)p1a[0], (bf16_t)p1a[1], (bf16_t)p1a[2], (bf16_t)p1a[3],
                       (bf16_t)p1b[0], (bf16_t)p1b[1], (bf16_t)p1b[2], (bf16_t)p1b[3] };
        __builtin_amdgcn_s_setprio(1);
#pragma unroll
        for (int tk = 0; tk < 4; ++tk) {
            uint32_t base = (uint32_t)((tk * 16 + c) * 128 + g * 16);
            bf16x8 b0 = *reinterpret_cast<const bf16x8*>(vb + (base ^ rm));
            bf16x8 b1 = *reinterpret_cast<const bf16x8*>(vb + ((base + 64) ^ rm));
            oacc[tk] = MFMA16(pa0, b0, oacc[tk]);
            oacc[tk] = MFMA16(pa1, b1, oacc[tk]);
        }
        __builtin_amdgcn_s_setprio(0);
        if (t + 2 < NT)       asm volatile("s_waitcnt vmcnt(6)" ::: "memory");
        else if (t + 1 < NT)  asm volatile("s_waitcnt vmcnt(4)" ::: "memory");
        asm volatile("s_waitcnt lgkmcnt(0)" ::: "memory");
        __builtin_amdgcn_sched_barrier(0);
        __builtin_amdgcn_s_barrier();
        bc = (bc == 2) ? 0 : bc + 1;
    }

#pragma unroll
    for (int tk = 0; tk < 4; ++tk) {
#pragma unroll
        for (int r = 0; r < 4; ++r) {
            int q = q0 + g * 4 + r;
            ctx[((size_t)b * S_ + q) * D_ + h * DK_ + tk * 16 + c] = (bf16_t)oacc[tk][r];
        }
    }
}

// ---------------------------------------------------------------------------
// LayerNorm over last dim (1024), 4096 rows
// ---------------------------------------------------------------------------
__global__ void ln_kernel(const float* __restrict__ x, const float* __restrict__ gamma,
                          const float* __restrict__ beta, float* __restrict__ out)
{
    int row = blockIdx.x;
    const float* xr = x + (size_t)row * D_;
    int tid = threadIdx.x;
    float v[4];
    float s = 0.f;
#pragma unroll
    for (int i = 0; i < 4; ++i) {
        v[i] = xr[tid + i * 256];
        s += v[i];
    }
#pragma unroll
    for (int off = 32; off > 0; off >>= 1) s += __shfl_xor(s, off);
    __shared__ float red[4];
    int wid = tid >> 6, lane = tid & 63;
    if (lane == 0) red[wid] = s;
    __syncthreads();
    float mu = (red[0] + red[1] + red[2] + red[3]) * (1.0f / D_);
    float vs = 0.f;
#pragma unroll
    for (int i = 0; i < 4; ++i) {
        float d = v[i] - mu;
        vs += d * d;
    }
#pragma unroll
    for (int off = 32; off > 0; off >>= 1) vs += __shfl_xor(vs, off);
    __syncthreads();
    __shared__ float red2[4];
    if (lane == 0) red2[wid] = vs;
    __syncthreads();
    float var = (red2[0] + red2[1] + red2[2] + red2[3]) * (1.0f / D_);
    float rs = rsqrtf(var + EPS_);
#pragma unroll
    for (int i = 0; i < 4; ++i) {
        int c = tid + i * 256;
        out[(size_t)row * D_ + c] = (v[i] - mu) * rs * gamma[c] + beta[c];
    }
}

extern "C" void kernel_launch(void* const* d_in, const int* in_sizes, int n_in,
                              void* d_out, int out_size, void* d_ws, size_t ws_size,
                              hipStream_t stream) {
    const float* q    = (const float*)d_in[0];
    const float* k    = (const float*)d_in[1];
    const float* v    = (const float*)d_in[2];
    const int*   mask = (const int*)d_in[3];
    const float* Wq   = (const float*)d_in[4];
    const float* bq   = (const float*)d_in[5];
    const float* Wk   = (const float*)d_in[6];
    const float* bk   = (const float*)d_in[7];
    const float* Wv   = (const float*)d_in[8];
    const float* bv   = (const float*)d_in[9];
    const float* Wo   = (const float*)d_in[10];
    const float* bo   = (const float*)d_in[11];
    const float* gamma= (const float*)d_in[12];
    const float* beta = (const float*)d_in[13];

    float* out  = (float*)d_out;                       // [B,S,D]
    float* attn = out + (size_t)B_ * S_ * D_;          // [B,H,S,S]

    uint8_t* ws = (uint8_t*)d_ws;
    bf16_t* xq  = (bf16_t*)(ws);
    bf16_t* xk  = (bf16_t*)(ws + ((size_t)8  << 20));
    bf16_t* xv  = (bf16_t*)(ws + ((size_t)16 << 20));
    bf16_t* wqb = (bf16_t*)(ws + ((size_t)24 << 20));
    bf16_t* wkb = (bf16_t*)(ws + ((size_t)26 << 20));
    bf16_t* wvb = (bf16_t*)(ws + ((size_t)28 << 20));
    bf16_t* wob = (bf16_t*)(ws + ((size_t)30 << 20));
    bf16_t* qh  = (bf16_t*)(ws + ((size_t)32 << 20));
    u16*    bits= (u16*)   (ws + ((size_t)40 << 20));
    bf16_t* kh  = (bf16_t*)(ws + ((size_t)42 << 20));
    bf16_t* vt  = (bf16_t*)(ws + ((size_t)50 << 20));
    bf16_t* ctx = (bf16_t*)(ws);                       // over xq (dead)
    float*  x   = (float*) (ws + ((size_t)8 << 20));   // over xk+xv (dead)

    dim3 blk(256);
    cvt3<<<dim3(6144), blk, 0, stream>>>(q, k, v, xq, xk, xv);
    cvt4<<<dim3(2048), blk, 0, stream>>>(Wq, Wk, Wv, Wo, wqb, wkb, wvb, wob);
    mask_pack<<<dim3((B_ * S_ * S_) / 256), blk, 0, stream>>>(mask, bits);

    // fused QKV: 768 blocks concurrent
    dim3 gqkv(D_ / 128, (B_ * S_) / 128, 3);           // (8, 32, 3)
    qkv_gemm<<<gqkv, blk, 0, stream>>>(xq, xk, xv, wqb, wkb, wvb,
                                       bq, bk, bv, qh, kh, vt);

    fused_attn<<<dim3(512), dim3(512), 0, stream>>>(qh, kh, vt, bits, attn, ctx);

    dim3 ggemm(D_ / 128, (B_ * S_) / 128);             // (8, 32)
    oproj_gemm<<<ggemm, blk, 0, stream>>>(ctx, wob, bo, q, x);
    ln_kernel<<<dim3(B_ * S_), blk, 0, stream>>>(x, gamma, beta, out);
}